// Round 2
// baseline (414.763 us; speedup 1.0000x reference)
//
#include <hip/hip_runtime.h>
#include <hip/hip_bf16.h>

typedef __attribute__((ext_vector_type(4))) float f32x4;
typedef __attribute__((ext_vector_type(8))) short short8;
typedef __attribute__((ext_vector_type(4))) unsigned short us4;
typedef unsigned short u16;

#define DEVI __device__ __forceinline__

#define BB 128      // batches
#define NN 256      // input patches per batch
#define MMEM 8      // memory tokens
#define DD 768      // embed dim
#define TT 264      // N + M
#define TP 320      // T padded to K-step multiple (zeros in P cols 264..319)
#define SP 384      // S col padding (3 x 128 tiles)
#define MAROWS 32896  // 257*128: 32768 x-rows + 8 memory rows + zero pad

DEVI u16 f2bf(float f) {
  __hip_bfloat16 b = __float2bfloat16(f);
  u16 u; __builtin_memcpy(&u, &b, 2); return u;
}

DEVI void gload_lds16(const void* g, void* l) {
  __builtin_amdgcn_global_load_lds((const __attribute__((address_space(1))) void*)g,
                                   (__attribute__((address_space(3))) void*)l, 16, 0, 0);
}

// ---------------- conversion kernels ----------------

__global__ __launch_bounds__(256)
void conv_x(const float* __restrict__ x, const float* __restrict__ mem, u16* __restrict__ Ab) {
  const long total4 = (long)MAROWS * DD / 4;
  for (long i = (long)blockIdx.x * blockDim.x + threadIdx.x; i < total4;
       i += (long)gridDim.x * blockDim.x) {
    long e = i * 4;
    int row = (int)(e / DD);
    int cb  = (int)(e % DD);
    f32x4 v = {0.f, 0.f, 0.f, 0.f};
    if (row < BB * NN)            v = *(const f32x4*)(x   + (size_t)row * DD + cb);
    else if (row < BB * NN + MMEM) v = *(const f32x4*)(mem + (size_t)(row - BB * NN) * DD + cb);
    us4 o = {f2bf(v[0]), f2bf(v[1]), f2bf(v[2]), f2bf(v[3])};
    *(us4*)(Ab + e) = o;
  }
}

__global__ __launch_bounds__(256)
void conv_w(const float* __restrict__ Wq, const float* __restrict__ Wk,
            const float* __restrict__ Wv, const float* __restrict__ Wo,
            u16* __restrict__ Wqt, u16* __restrict__ Wkt,
            u16* __restrict__ Wvt, u16* __restrict__ Wot) {
  const int total = 4 * DD * DD;
  for (int i = blockIdx.x * blockDim.x + threadIdx.x; i < total;
       i += gridDim.x * blockDim.x) {
    int mat = i / (DD * DD), rem = i % (DD * DD);
    int j = rem / DD, d = rem % DD;
    const float* W = (mat == 0) ? Wq : (mat == 1) ? Wk : (mat == 2) ? Wv : Wo;
    u16* Wt = (mat == 0) ? Wqt : (mat == 1) ? Wkt : (mat == 2) ? Wvt : Wot;
    Wt[(size_t)j * DD + d] = f2bf(W[(size_t)d * DD + j]);
  }
}

// ---------------- generic B^T GEMM (m97-style: 128x128 tile, BK=32) ----------------
// MODE 0: QKV projection.  A=Ab[32896,768].  B = Wqt/Wkt/Wvt by tn.  out bf16 Q/K/V (+bias).
// MODE 1: S = Q @ K^T * scale, batched.  B rows remapped for [x;memory] concat.  out fp32 S.
// MODE 2: O = P @ Vt^T, batched, K=320.  out bf16 O.
// MODE 3: out = O @ Wot^T + bo.  out fp32 d_out.

template<int MODE>
__global__ __launch_bounds__(256)
void gemm_bt(const u16* __restrict__ A, const u16* __restrict__ Bm,
             const u16* __restrict__ B1, const u16* __restrict__ B2,
             const float* __restrict__ f0, const float* __restrict__ f1,
             const float* __restrict__ f2,
             u16* __restrict__ U0, u16* __restrict__ U1, u16* __restrict__ U2,
             float* __restrict__ F0, int Kdim)
{
  const int tid = threadIdx.x;
  const int l  = tid & 63;
  const int w  = tid >> 6;
  const int wm = w >> 1, wn = w & 1;
  const int tm = blockIdx.x, tn = blockIdx.y, z = blockIdx.z;

  __shared__ u16 lsA[128 * 32];
  __shared__ u16 lsB[128 * 32];

  const u16* Abase; int lda;
  if constexpr (MODE == 1)      { Abase = A + ((size_t)z * NN + tm * 128) * DD; lda = DD; }
  else if constexpr (MODE == 2) { Abase = A + ((size_t)z * NN + tm * 128) * TP; lda = TP; }
  else                          { Abase = A + (size_t)tm * 128 * DD;            lda = DD; }

  const u16* Bbase; int ldb;
  if constexpr (MODE == 0) {
    const u16* W = (tn < 6) ? Bm : (tn < 12 ? B1 : B2);
    Bbase = W + (size_t)((tn % 6) * 128) * DD; ldb = DD;
  } else if constexpr (MODE == 1) { Bbase = Bm; ldb = DD; }
  else if constexpr (MODE == 2) { Bbase = Bm + ((size_t)z * DD + tn * 128) * TP; ldb = TP; }
  else                          { Bbase = Bm + (size_t)tn * 128 * DD; ldb = DD; }

  f32x4 acc[4][4];
  #pragma unroll
  for (int i = 0; i < 4; i++)
    #pragma unroll
    for (int j = 0; j < 4; j++) acc[i][j] = (f32x4){0.f, 0.f, 0.f, 0.f};

  const int srow = l >> 2;          // staging row-within-16 block
  const int scol = (l & 3) * 8;     // staging col (u16)
  const int nkt = Kdim >> 5;

  for (int kt = 0; kt < nkt; ++kt) {
    const int kpos = kt * 32 + scol;
    #pragma unroll
    for (int q = 0; q < 2; ++q) {
      const int r = q * 64 + w * 16 + srow;
      const u16* src = Abase + (size_t)r * lda + kpos;
      gload_lds16(src, &lsA[q * 2048 + w * 512]);
    }
    #pragma unroll
    for (int q = 0; q < 2; ++q) {
      const int r = q * 64 + w * 16 + srow;
      const u16* src;
      if constexpr (MODE == 1) {
        const int t = tn * 128 + r;
        const int rr = (t < NN) ? (z * NN + t)
                     : ((t < TT) ? (BB * NN + t - NN) : BB * NN);
        src = Bm + (size_t)rr * DD + kpos;
      } else {
        src = Bbase + (size_t)r * ldb + kpos;
      }
      gload_lds16(src, &lsB[q * 2048 + w * 512]);
    }
    __syncthreads();

    const int fr = l & 15, fk = (l >> 4) * 8;
    short8 fa[4], fb[4];
    #pragma unroll
    for (int mi = 0; mi < 4; mi++)
      fa[mi] = *(const short8*)&lsA[(wm * 64 + mi * 16 + fr) * 32 + fk];
    #pragma unroll
    for (int ni = 0; ni < 4; ni++)
      fb[ni] = *(const short8*)&lsB[(wn * 64 + ni * 16 + fr) * 32 + fk];
    #pragma unroll
    for (int mi = 0; mi < 4; mi++)
      #pragma unroll
      for (int ni = 0; ni < 4; ni++)
        acc[mi][ni] = __builtin_amdgcn_mfma_f32_16x16x32_bf16(fa[mi], fb[ni], acc[mi][ni], 0, 0, 0);
    __syncthreads();
  }

  const int fr  = l & 15;
  const int fro = (l >> 4) * 4;

  if constexpr (MODE == 0) {
    const int mat = tn / 6;
    const float* bias = (mat == 0) ? f0 : (mat == 1 ? f1 : f2);
    u16* ob = (mat == 0) ? U0 : (mat == 1 ? U1 : U2);
    const int cb = (tn % 6) * 128 + wn * 64;
    const size_t rb = (size_t)tm * 128 + wm * 64;
    #pragma unroll
    for (int mi = 0; mi < 4; mi++)
      #pragma unroll
      for (int ni = 0; ni < 4; ni++) {
        const int col = cb + ni * 16 + fr;
        const float bvv = bias[col];
        #pragma unroll
        for (int r = 0; r < 4; r++)
          ob[(rb + mi * 16 + fro + r) * DD + col] = f2bf(acc[mi][ni][r] + bvv);
      }
  } else if constexpr (MODE == 1) {
    const float scl = 0.03608439182435161f;  // 768^-0.5
    float* Sb = F0 + (size_t)z * NN * SP;
    const int cb = tn * 128 + wn * 64;
    const int rb = tm * 128 + wm * 64;
    #pragma unroll
    for (int mi = 0; mi < 4; mi++)
      #pragma unroll
      for (int ni = 0; ni < 4; ni++)
        #pragma unroll
        for (int r = 0; r < 4; r++)
          Sb[(size_t)(rb + mi * 16 + fro + r) * SP + cb + ni * 16 + fr] = acc[mi][ni][r] * scl;
  } else if constexpr (MODE == 2) {
    const int cb = tn * 128 + wn * 64;
    const size_t rb = (size_t)z * NN + tm * 128 + wm * 64;
    #pragma unroll
    for (int mi = 0; mi < 4; mi++)
      #pragma unroll
      for (int ni = 0; ni < 4; ni++)
        #pragma unroll
        for (int r = 0; r < 4; r++)
          U0[(rb + mi * 16 + fro + r) * DD + cb + ni * 16 + fr] = f2bf(acc[mi][ni][r]);
  } else {
    const int cb = tn * 128 + wn * 64;
    const size_t rb = (size_t)tm * 128 + wm * 64;
    #pragma unroll
    for (int mi = 0; mi < 4; mi++)
      #pragma unroll
      for (int ni = 0; ni < 4; ni++) {
        const int col = cb + ni * 16 + fr;
        const float bvv = f0[col];
        #pragma unroll
        for (int r = 0; r < 4; r++)
          F0[(rb + mi * 16 + fro + r) * DD + col] = acc[mi][ni][r] + bvv;
      }
  }
}

// ---------------- softmax: one wave per row of S[32768][384], cols 0..263 valid ----------------

__global__ __launch_bounds__(256)
void softmax_k(const float* __restrict__ S, u16* __restrict__ P) {
  const int l = threadIdx.x & 63;
  const int row = blockIdx.x * 4 + (threadIdx.x >> 6);
  const float* s = S + (size_t)row * SP;
  float v0 = s[l], v1 = s[64 + l], v2 = s[128 + l], v3 = s[192 + l];
  float v4 = (l < 8) ? s[256 + l] : -__builtin_inff();
  float m = fmaxf(fmaxf(fmaxf(v0, v1), fmaxf(v2, v3)), v4);
  #pragma unroll
  for (int off = 32; off; off >>= 1) m = fmaxf(m, __shfl_xor(m, off));
  float e0 = __expf(v0 - m), e1 = __expf(v1 - m), e2 = __expf(v2 - m), e3 = __expf(v3 - m);
  float e4 = (l < 8) ? __expf(v4 - m) : 0.f;
  float sum = e0 + e1 + e2 + e3 + e4;
  #pragma unroll
  for (int off = 32; off; off >>= 1) sum += __shfl_xor(sum, off);
  const float inv = 1.f / sum;
  u16* p = P + (size_t)row * TP;
  p[l] = f2bf(e0 * inv); p[64 + l] = f2bf(e1 * inv);
  p[128 + l] = f2bf(e2 * inv); p[192 + l] = f2bf(e3 * inv);
  if (l < 8) p[256 + l] = f2bf(e4 * inv);
  else       p[256 + l] = 0;            // zero pad cols 264..319
}

// ---------------- V transpose: Vt[b][d][t] (t padded to 320 with zeros) ----------------

__global__ __launch_bounds__(256)
void transpose_v(const u16* __restrict__ V, u16* __restrict__ Vt) {
  __shared__ u16 ls[64 * 66];
  const int b = blockIdx.z;
  const int d0 = blockIdx.x * 64;
  const int t0 = blockIdx.y * 64;
  const int tid = threadIdx.x;
  #pragma unroll
  for (int q = 0; q < 2; ++q) {
    const int idx = q * 256 + tid;
    const int tr = idx >> 3;
    const int dg = (idx & 7) * 8;
    const int t = t0 + tr;
    short8 v = (short8)(short)0;
    if (t < NN)       v = *(const short8*)(V + ((size_t)b * NN + t) * DD + d0 + dg);
    else if (t < TT)  v = *(const short8*)(V + (size_t)(BB * NN + t - NN) * DD + d0 + dg);
    #pragma unroll
    for (int e = 0; e < 8; ++e) ls[tr * 66 + dg + e] = (u16)v[e];
  }
  __syncthreads();
  #pragma unroll
  for (int q = 0; q < 2; ++q) {
    const int idx = q * 256 + tid;
    const int dr = idx >> 3;
    const int tg = (idx & 7) * 8;
    short8 v;
    #pragma unroll
    for (int e = 0; e < 8; ++e) v[e] = (short)ls[(tg + e) * 66 + dr];
    *(short8*)(Vt + ((size_t)b * DD + d0 + dr) * TP + t0 + tg) = v;
  }
}

// ---------------- launch ----------------
//
// Workspace budget was the round-1 bug: 269.7 MB of carves overran ws_size;
// the OOB tail (weight buffers, written EARLY each call by conv_w) corrupted
// adjacent allocations (inputs), which call 1 had already consumed (so it
// passed) but replays re-read (so they diverged).
//
// New plan, 156.3 MB of ws + d_out used as scratch for dead-before-G3 tensors:
//   d_out (100.66 MB): Ab [0,50.53M) live conv_x->G1; S [0,50.33M) live
//     G2a->softmax; P [50.53M,71.50M) live softmax->G2c. All dead before G3
//     overwrites d_out.
//   ws: Qb@0, Kb@50.53M, Vb@101.06M (each 50.53M, live G1->G2a / ->transpose);
//       Vt@0 (62.91M, over dead Qb+Kb, live transpose->G2c);
//       O@62.91M (50.33M, over dead Kb-tail+Vb, live G2c->G3);
//       W^T x4 @151.58M (4.72M). Total 156.30 MB.

extern "C" void kernel_launch(void* const* d_in, const int* in_sizes, int n_in,
                              void* d_out, int out_size, void* d_ws, size_t ws_size,
                              hipStream_t stream) {
  const float* x   = (const float*)d_in[0];
  const float* mem = (const float*)d_in[1];
  const float* Wq  = (const float*)d_in[2];
  const float* bq  = (const float*)d_in[3];
  const float* Wk  = (const float*)d_in[4];
  const float* bk  = (const float*)d_in[5];
  const float* Wv  = (const float*)d_in[6];
  const float* bv  = (const float*)d_in[7];
  const float* Wo  = (const float*)d_in[8];
  const float* bo  = (const float*)d_in[9];
  float* out = (float*)d_out;
  (void)ws_size; (void)in_sizes; (void)n_in; (void)out_size;

  const size_t QKV_B = (size_t)MAROWS * DD * 2;       // 50,528,256
  char* wsb = (char*)d_ws;
  u16* Qb = (u16*)(wsb);
  u16* Kb = (u16*)(wsb + QKV_B);
  u16* Vb = (u16*)(wsb + 2 * QKV_B);
  u16* Vt = (u16*)(wsb);                              // over dead Qb+Kb head
  u16* O  = (u16*)(wsb + (size_t)BB * DD * TP * 2);   // @62,914,560, over dead Kb tail+Vb
  u16* Wqt = (u16*)(wsb + 3 * QKV_B);                 // @151,584,768
  u16* Wkt = Wqt + (size_t)DD * DD;
  u16* Wvt = Wkt + (size_t)DD * DD;
  u16* Wot = Wvt + (size_t)DD * DD;

  u16*   Ab = (u16*)d_out;                            // live conv_x -> G1
  float* S  = (float*)d_out;                          // live G2a -> softmax
  u16*   P  = (u16*)((char*)d_out + QKV_B);           // live softmax -> G2c

  conv_x<<<2048, 256, 0, stream>>>(x, mem, Ab);
  conv_w<<<1024, 256, 0, stream>>>(Wq, Wk, Wv, Wo, Wqt, Wkt, Wvt, Wot);

  // G1: QKV projection  [32896 x 2304] = Ab @ [Wqt|Wkt|Wvt]^T  (+bias, -> bf16)
  gemm_bt<0><<<dim3(257, 18, 1), 256, 0, stream>>>(
      Ab, Wqt, Wkt, Wvt, bq, bk, bv, Qb, Kb, Vb, nullptr, DD);

  // G2a: S = Q @ K^T * scale  (per batch, K-rows remapped over [x;memory])
  gemm_bt<1><<<dim3(2, 3, BB), 256, 0, stream>>>(
      Qb, Kb, nullptr, nullptr, nullptr, nullptr, nullptr,
      nullptr, nullptr, nullptr, S, DD);

  // softmax rows -> P (bf16, zero-padded to 320 cols)
  softmax_k<<<8192, 256, 0, stream>>>(S, P);

  // Vt[b][d][t]  (writes over dead Qb/Kb region)
  transpose_v<<<dim3(12, 5, BB), 256, 0, stream>>>(Vb, Vt);

  // G2c: O = P @ Vt^T  (per batch, K=320)
  gemm_bt<2><<<dim3(2, 6, BB), 256, 0, stream>>>(
      P, Vt, nullptr, nullptr, nullptr, nullptr, nullptr,
      O, nullptr, nullptr, nullptr, TP);

  // G3: out = O @ Wot^T + bo  (fp32)
  gemm_bt<3><<<dim3(256, 6, 1), 256, 0, stream>>>(
      O, Wot, nullptr, nullptr, bo, nullptr, nullptr,
      nullptr, nullptr, nullptr, out, DD);
}

// Round 3
// 365.078 us; speedup vs baseline: 1.1361x; 1.1361x over previous
//
#include <hip/hip_runtime.h>
#include <hip/hip_bf16.h>

typedef __attribute__((ext_vector_type(4))) float f32x4;
typedef __attribute__((ext_vector_type(8))) short short8;
typedef __attribute__((ext_vector_type(4))) unsigned short us4;
typedef unsigned short u16;

#define DEVI __device__ __forceinline__

#define BB 128      // batches
#define NN 256      // input patches per batch
#define MMEM 8      // memory tokens
#define DD 768      // embed dim
#define TT 264      // N + M
#define TP 320      // T padded (zeros in P cols 264..319)
#define SP 384      // S col padding (3 x 128 tiles)
#define MAROWS 32896
#define AROWS2 33024  // 129*256: rows for the 256-tile GEMMs (x .. memory .. zero pad)

DEVI u16 f2bf(float f) {
  __hip_bfloat16 b = __float2bfloat16(f);
  u16 u; __builtin_memcpy(&u, &b, 2); return u;
}

DEVI void gload_lds16(const void* g, void* l) {
  __builtin_amdgcn_global_load_lds((const __attribute__((address_space(1))) void*)g,
                                   (__attribute__((address_space(3))) void*)l, 16, 0, 0);
}

// ---------------- conversion kernels ----------------

__global__ __launch_bounds__(256)
void conv_x(const float* __restrict__ x, const float* __restrict__ mem, u16* __restrict__ Ab) {
  const long total4 = (long)AROWS2 * DD / 4;
  for (long i = (long)blockIdx.x * blockDim.x + threadIdx.x; i < total4;
       i += (long)gridDim.x * blockDim.x) {
    long e = i * 4;
    int row = (int)(e / DD);
    int cb  = (int)(e % DD);
    f32x4 v = {0.f, 0.f, 0.f, 0.f};
    if (row < BB * NN)             v = *(const f32x4*)(x   + (size_t)row * DD + cb);
    else if (row < BB * NN + MMEM) v = *(const f32x4*)(mem + (size_t)(row - BB * NN) * DD + cb);
    us4 o = {f2bf(v[0]), f2bf(v[1]), f2bf(v[2]), f2bf(v[3])};
    *(us4*)(Ab + e) = o;
  }
}

__global__ __launch_bounds__(256)
void conv_w(const float* __restrict__ Wq, const float* __restrict__ Wk,
            const float* __restrict__ Wv, const float* __restrict__ Wo,
            u16* __restrict__ Wqt, u16* __restrict__ Wkt,
            u16* __restrict__ Wvt, u16* __restrict__ Wot) {
  const int total = 4 * DD * DD;
  for (int i = blockIdx.x * blockDim.x + threadIdx.x; i < total;
       i += gridDim.x * blockDim.x) {
    int mat = i / (DD * DD), rem = i % (DD * DD);
    int j = rem / DD, d = rem % DD;
    const float* W = (mat == 0) ? Wq : (mat == 1) ? Wk : (mat == 2) ? Wv : Wo;
    u16* Wt = (mat == 0) ? Wqt : (mat == 1) ? Wkt : (mat == 2) ? Wvt : Wot;
    Wt[(size_t)j * DD + d] = f2bf(W[(size_t)d * DD + j]);
  }
}

// ================= 256x256 8-wave phase-pipelined B^T GEMM (K = 768) =================
// T2 st_16x32 swizzle + T3/T4 counted vmcnt + T5 setprio.
// LDS: 2 slots x (A 32KB + B 32KB) = 128KB dynamic. Subtile = 16 rows x 32 cols bf16
// = 1024B = exactly one global_load_lds(16B) instruction. Swizzle byte^=((byte>>9)&1)<<5
// applied via permuted per-lane SOURCE addresses (linear LDS dest) and on ds_read addr.
// MODE 0: QKV projection (A=Ab, B by tn/3 among Wq/Wk/Wv^T, bias, bf16 out x3)
// MODE 1: out = A @ B^T + bias (fp32 out)

#define BAR()   __builtin_amdgcn_s_barrier()
#define SCB()   __builtin_amdgcn_sched_barrier(0)
#define LGKM0() asm volatile("s_waitcnt lgkmcnt(0)" ::: "memory")
#define VM4()   asm volatile("s_waitcnt vmcnt(4)" ::: "memory")

#define STG(gb, isB, ss, rg, kt) do {                                          \
    const u16* _s = (gb) + (size_t)((rg) * 16 + srow) * DD + (kt) * 64 + scol; \
    char* _d = smem + (ss) * 65536 + (isB) * 32768 + (rg) * 2048;              \
    gload_lds16(_s, _d);                                                       \
    gload_lds16(_s + 32, _d + 1024);                                           \
  } while (0)

// staging subtile sets (consumption-ordered): wave w stages rg, both col-groups
#define STG_A0(ss, kt) STG(Ab, 0, ss, ((w & 3) | ((w & 4) << 1)), kt)
#define STG_B0(ss, kt) STG(Bb, 1, ss, ((w & 1) | ((w & 6) << 1)), kt)
#define STG_A1(ss, kt) STG(Ab, 0, ss, (((w & 3) | ((w & 4) << 1)) + 4), kt)
#define STG_B1(ss, kt) STG(Bb, 1, ss, (((w & 1) | ((w & 6) << 1)) + 2), kt)

#define RD_A(dst, s, QM)                                                          \
  _Pragma("unroll") for (int mi = 0; mi < 4; ++mi)                                \
  _Pragma("unroll") for (int ks = 0; ks < 2; ++ks)                                \
    dst[mi][ks] = *(const short8*)(smem + (s) * 65536 +                           \
                    ((wm * 8 + (QM) * 4 + mi) * 2 + ks) * 1024 + fbase);

#define RD_B(dst, s, QN)                                                          \
  _Pragma("unroll") for (int ni = 0; ni < 2; ++ni)                                \
  _Pragma("unroll") for (int ks = 0; ks < 2; ++ks)                                \
    dst[ni][ks] = *(const short8*)(smem + (s) * 65536 + 32768 +                   \
                    ((wn * 4 + (QN) * 2 + ni) * 2 + ks) * 1024 + fbase);

#define MM(FA, FB, QM, QN)                                                        \
  _Pragma("unroll") for (int mi = 0; mi < 4; ++mi)                                \
  _Pragma("unroll") for (int ni = 0; ni < 2; ++ni)                                \
  _Pragma("unroll") for (int ks = 0; ks < 2; ++ks)                                \
    acc[(QM)*4+mi][(QN)*2+ni] = __builtin_amdgcn_mfma_f32_16x16x32_bf16(          \
        FA[mi][ks], FB[ni][ks], acc[(QM)*4+mi][(QN)*2+ni], 0, 0, 0);

template<int MODE>
__global__ __launch_bounds__(512)
void gemm256(const u16* __restrict__ A, const u16* __restrict__ Bq,
             const u16* __restrict__ Bk, const u16* __restrict__ Bv,
             const float* __restrict__ b0, const float* __restrict__ b1,
             const float* __restrict__ b2,
             u16* __restrict__ Oq, u16* __restrict__ Ok, u16* __restrict__ Ov,
             float* __restrict__ FO, int NT)
{
  extern __shared__ char smem[];
  const int tid = threadIdx.x;
  const int l = tid & 63;
  const int w = tid >> 6;           // wave 0..7
  const int wm = w >> 2, wn = w & 3;
  const int tn = blockIdx.x, tm = blockIdx.y;

  const u16* Ab = A + (size_t)tm * 256 * DD;
  const u16* Bb;
  int matsel = 0;
  if constexpr (MODE == 0) {
    matsel = tn / 3;
    const u16* Wp = (matsel == 0) ? Bq : (matsel == 1) ? Bk : Bv;
    Bb = Wp + (size_t)(tn % 3) * 256 * DD;
  } else {
    Bb = Bq + (size_t)tn * 256 * DD;
  }

  // staging lane constants: lane i writes LDS subtile bytes [16i,16i+16); its
  // pre-swizzled source chunk is j = i (i<32) else i^2.
  const int jj = (l < 32) ? l : (l ^ 2);
  const int srow = jj >> 2;
  const int scol = (jj & 3) * 8;
  // frag ds_read byte base within a subtile, swizzled
  const int fbase = (((l & 15) * 64) + ((l >> 4) * 16)) ^ (((l >> 3) & 1) << 5);

  f32x4 acc[8][4];
  #pragma unroll
  for (int i = 0; i < 8; ++i)
    #pragma unroll
    for (int jx = 0; jx < 4; ++jx) acc[i][jx] = (f32x4){0.f, 0.f, 0.f, 0.f};

  short8 fa0[4][2], fa1[4][2], fb0[2][2], fb1[2][2];

  // prologue: stage K-tile 0 into slot 0 (sets A0,B0,A1,B1)
  STG_A0(0, 0); STG_B0(0, 0); STG_A1(0, 0); STG_B1(0, 0);
  VM4(); BAR(); SCB();

  for (int g = 0; g < NT; ++g) {
    const int s = g & 1, ss = s ^ 1;
    const int st = (g + 1 < NT) ? (g + 1) : 0;   // clamp: last group stages a dead tile

    // phase 0: quadrant (0,0)
    RD_A(fa0, s, 0); RD_B(fb0, s, 0);
    STG_A0(ss, st);
    SCB(); BAR(); LGKM0(); SCB();
    __builtin_amdgcn_s_setprio(1); MM(fa0, fb0, 0, 0); __builtin_amdgcn_s_setprio(0);
    SCB(); VM4(); BAR(); SCB();

    // phase 1: quadrant (1,0)
    RD_A(fa1, s, 1);
    STG_B0(ss, st);
    SCB(); BAR(); LGKM0(); SCB();
    __builtin_amdgcn_s_setprio(1); MM(fa1, fb0, 1, 0); __builtin_amdgcn_s_setprio(0);
    SCB(); VM4(); BAR(); SCB();

    // phase 2: quadrant (1,1)
    RD_B(fb1, s, 1);
    STG_A1(ss, st);
    SCB(); BAR(); LGKM0(); SCB();
    __builtin_amdgcn_s_setprio(1); MM(fa1, fb1, 1, 1); __builtin_amdgcn_s_setprio(0);
    SCB(); BAR(); SCB();

    // phase 3: quadrant (0,1)
    STG_B1(ss, st);
    SCB(); BAR(); LGKM0(); SCB();
    __builtin_amdgcn_s_setprio(1); MM(fa0, fb1, 0, 1); __builtin_amdgcn_s_setprio(0);
    SCB(); VM4(); BAR(); SCB();
  }

  // epilogue
  const int fr = l & 15, fro = (l >> 4) * 4;
  if constexpr (MODE == 0) {
    const float* bias = (matsel == 0) ? b0 : (matsel == 1) ? b1 : b2;
    u16* ob = (matsel == 0) ? Oq : (matsel == 1) ? Ok : Ov;
    const int cb = (tn % 3) * 256 + wn * 64;
    const size_t rb = (size_t)tm * 256 + wm * 128;
    #pragma unroll
    for (int MI = 0; MI < 8; ++MI)
      #pragma unroll
      for (int NI = 0; NI < 4; ++NI) {
        const int col = cb + NI * 16 + fr;
        const float bvv = bias[col];
        #pragma unroll
        for (int r = 0; r < 4; ++r)
          ob[(rb + MI * 16 + fro + r) * DD + col] = f2bf(acc[MI][NI][r] + bvv);
      }
  } else {
    const int cb = tn * 256 + wn * 64;
    const size_t rb = (size_t)tm * 256 + wm * 128;
    #pragma unroll
    for (int MI = 0; MI < 8; ++MI)
      #pragma unroll
      for (int NI = 0; NI < 4; ++NI) {
        const int col = cb + NI * 16 + fr;
        const float bvv = b0[col];
        #pragma unroll
        for (int r = 0; r < 4; ++r)
          FO[(rb + MI * 16 + fro + r) * DD + col] = acc[MI][NI][r] + bvv;
      }
  }
}

// ---------------- old 128x128 B^T GEMM (kept for batched S and PV) ----------------
// MODE 1: S = Q @ K^T * scale, batched, K-rows remapped.  out fp32 S.
// MODE 2: O = P @ Vt^T, batched, K=320.  out bf16 O.

template<int MODE>
__global__ __launch_bounds__(256)
void gemm_bt(const u16* __restrict__ A, const u16* __restrict__ Bm,
             const float* __restrict__ f0,
             u16* __restrict__ U0, float* __restrict__ F0, int Kdim)
{
  const int tid = threadIdx.x;
  const int l  = tid & 63;
  const int w  = tid >> 6;
  const int wm = w >> 1, wn = w & 1;
  const int tm = blockIdx.x, tn = blockIdx.y, z = blockIdx.z;

  __shared__ u16 lsA[128 * 32];
  __shared__ u16 lsB[128 * 32];

  const u16* Abase; int lda;
  if constexpr (MODE == 1)      { Abase = A + ((size_t)z * NN + tm * 128) * DD; lda = DD; }
  else                          { Abase = A + ((size_t)z * NN + tm * 128) * TP; lda = TP; }

  const u16* Bbase; int ldb;
  if constexpr (MODE == 1) { Bbase = Bm; ldb = DD; }
  else                     { Bbase = Bm + ((size_t)z * DD + tn * 128) * TP; ldb = TP; }

  f32x4 acc[4][4];
  #pragma unroll
  for (int i = 0; i < 4; i++)
    #pragma unroll
    for (int j = 0; j < 4; j++) acc[i][j] = (f32x4){0.f, 0.f, 0.f, 0.f};

  const int srow = l >> 2;
  const int scol = (l & 3) * 8;
  const int nkt = Kdim >> 5;

  for (int kt = 0; kt < nkt; ++kt) {
    const int kpos = kt * 32 + scol;
    #pragma unroll
    for (int q = 0; q < 2; ++q) {
      const int r = q * 64 + w * 16 + srow;
      gload_lds16(Abase + (size_t)r * lda + kpos, &lsA[q * 2048 + w * 512]);
    }
    #pragma unroll
    for (int q = 0; q < 2; ++q) {
      const int r = q * 64 + w * 16 + srow;
      const u16* src;
      if constexpr (MODE == 1) {
        const int t = tn * 128 + r;
        const int rr = (t < NN) ? (z * NN + t)
                     : ((t < TT) ? (BB * NN + t - NN) : BB * NN);
        src = Bm + (size_t)rr * DD + kpos;
      } else {
        src = Bbase + (size_t)r * ldb + kpos;
      }
      gload_lds16(src, &lsB[q * 2048 + w * 512]);
    }
    __syncthreads();

    const int fr = l & 15, fk = (l >> 4) * 8;
    short8 fa[4], fb[4];
    #pragma unroll
    for (int mi = 0; mi < 4; mi++)
      fa[mi] = *(const short8*)&lsA[(wm * 64 + mi * 16 + fr) * 32 + fk];
    #pragma unroll
    for (int ni = 0; ni < 4; ni++)
      fb[ni] = *(const short8*)&lsB[(wn * 64 + ni * 16 + fr) * 32 + fk];
    #pragma unroll
    for (int mi = 0; mi < 4; mi++)
      #pragma unroll
      for (int ni = 0; ni < 4; ni++)
        acc[mi][ni] = __builtin_amdgcn_mfma_f32_16x16x32_bf16(fa[mi], fb[ni], acc[mi][ni], 0, 0, 0);
    __syncthreads();
  }

  const int fr  = l & 15;
  const int fro = (l >> 4) * 4;

  if constexpr (MODE == 1) {
    const float scl = 0.03608439182435161f;  // 768^-0.5
    float* Sb = F0 + (size_t)z * NN * SP;
    const int cb = tn * 128 + wn * 64;
    const int rb = tm * 128 + wm * 64;
    #pragma unroll
    for (int mi = 0; mi < 4; mi++)
      #pragma unroll
      for (int ni = 0; ni < 4; ni++)
        #pragma unroll
        for (int r = 0; r < 4; r++)
          Sb[(size_t)(rb + mi * 16 + fro + r) * SP + cb + ni * 16 + fr] = acc[mi][ni][r] * scl;
  } else {
    const int cb = tn * 128 + wn * 64;
    const size_t rb = (size_t)z * NN + tm * 128 + wm * 64;
    #pragma unroll
    for (int mi = 0; mi < 4; mi++)
      #pragma unroll
      for (int ni = 0; ni < 4; ni++)
        #pragma unroll
        for (int r = 0; r < 4; r++)
          U0[(rb + mi * 16 + fro + r) * DD + cb + ni * 16 + fr] = f2bf(acc[mi][ni][r]);
  }
}

// ---------------- softmax: one wave per row of S[32768][384], cols 0..263 valid ----------------

__global__ __launch_bounds__(256)
void softmax_k(const float* __restrict__ S, u16* __restrict__ P) {
  const int l = threadIdx.x & 63;
  const int row = blockIdx.x * 4 + (threadIdx.x >> 6);
  const float* s = S + (size_t)row * SP;
  float v0 = s[l], v1 = s[64 + l], v2 = s[128 + l], v3 = s[192 + l];
  float v4 = (l < 8) ? s[256 + l] : -__builtin_inff();
  float m = fmaxf(fmaxf(fmaxf(v0, v1), fmaxf(v2, v3)), v4);
  #pragma unroll
  for (int off = 32; off; off >>= 1) m = fmaxf(m, __shfl_xor(m, off));
  float e0 = __expf(v0 - m), e1 = __expf(v1 - m), e2 = __expf(v2 - m), e3 = __expf(v3 - m);
  float e4 = (l < 8) ? __expf(v4 - m) : 0.f;
  float sum = e0 + e1 + e2 + e3 + e4;
  #pragma unroll
  for (int off = 32; off; off >>= 1) sum += __shfl_xor(sum, off);
  const float inv = 1.f / sum;
  u16* p = P + (size_t)row * TP;
  p[l] = f2bf(e0 * inv); p[64 + l] = f2bf(e1 * inv);
  p[128 + l] = f2bf(e2 * inv); p[192 + l] = f2bf(e3 * inv);
  if (l < 8) p[256 + l] = f2bf(e4 * inv);
  else       p[256 + l] = 0;
}

// ---------------- V transpose: Vt[b][d][t] (t padded to 320 with zeros) ----------------

__global__ __launch_bounds__(256)
void transpose_v(const u16* __restrict__ V, u16* __restrict__ Vt) {
  __shared__ u16 ls[64 * 66];
  const int b = blockIdx.z;
  const int d0 = blockIdx.x * 64;
  const int t0 = blockIdx.y * 64;
  const int tid = threadIdx.x;
  #pragma unroll
  for (int q = 0; q < 2; ++q) {
    const int idx = q * 256 + tid;
    const int tr = idx >> 3;
    const int dg = (idx & 7) * 8;
    const int t = t0 + tr;
    short8 v = (short8)(short)0;
    if (t < NN)       v = *(const short8*)(V + ((size_t)b * NN + t) * DD + d0 + dg);
    else if (t < TT)  v = *(const short8*)(V + (size_t)(BB * NN + t - NN) * DD + d0 + dg);
    #pragma unroll
    for (int e = 0; e < 8; ++e) ls[tr * 66 + dg + e] = (u16)v[e];
  }
  __syncthreads();
  #pragma unroll
  for (int q = 0; q < 2; ++q) {
    const int idx = q * 256 + tid;
    const int dr = idx >> 3;
    const int tg = (idx & 7) * 8;
    short8 v;
    #pragma unroll
    for (int e = 0; e < 8; ++e) v[e] = (short)ls[(tg + e) * 66 + dr];
    *(short8*)(Vt + ((size_t)b * DD + d0 + dr) * TP + t0 + tg) = v;
  }
}

// ---------------- launch ----------------
// d_out (100.66 MB): Ab [0,50.72M) live conv_x->G1; S [0,50.33M) live G2a->softmax;
//   P [50.72M,71.70M) live softmax->G2c; Wq/Wk/Wv^T [97.12M,100.66M) live conv_w->G1.
//   All dead before G3 overwrites d_out.
// ws (high-water 153.35 MB, under round-2-proven 156.3 MB):
//   Qb@0, Kb@50.72M, Vb@101.45M (live G1 -> G2a/transpose);
//   Vt@0 (62.91M, over dead Qb+Kb-head); O@62.91M (50.33M, over dead Kb-tail+Vb-head);
//   Wot@152.17M (1.18M, live conv_w -> G3).

extern "C" void kernel_launch(void* const* d_in, const int* in_sizes, int n_in,
                              void* d_out, int out_size, void* d_ws, size_t ws_size,
                              hipStream_t stream) {
  const float* x   = (const float*)d_in[0];
  const float* mem = (const float*)d_in[1];
  const float* Wq  = (const float*)d_in[2];
  const float* bq  = (const float*)d_in[3];
  const float* Wk  = (const float*)d_in[4];
  const float* bk  = (const float*)d_in[5];
  const float* Wv  = (const float*)d_in[6];
  const float* bv  = (const float*)d_in[7];
  const float* Wo  = (const float*)d_in[8];
  const float* bo  = (const float*)d_in[9];
  float* out = (float*)d_out;
  (void)ws_size; (void)in_sizes; (void)n_in; (void)out_size;

  const size_t QKV_B = (size_t)AROWS2 * DD * 2;        // 50,724,864
  char* wsb = (char*)d_ws;
  u16* Qb  = (u16*)(wsb);
  u16* Kb  = (u16*)(wsb + QKV_B);
  u16* Vb  = (u16*)(wsb + 2 * QKV_B);
  u16* Vt  = (u16*)(wsb);                              // over dead Qb+Kb head
  u16* O   = (u16*)(wsb + (size_t)BB * DD * TP * 2);   // @62,914,560
  u16* Wot = (u16*)(wsb + 3 * QKV_B);                  // @152,174,592

  u16*   Ab  = (u16*)d_out;                            // live conv_x -> G1
  float* S   = (float*)d_out;                          // live G2a -> softmax
  u16*   P   = (u16*)((char*)d_out + QKV_B);           // live softmax -> G2c
  u16*   Wqt = (u16*)((char*)d_out + 97124352);        // live conv_w -> G1
  u16*   Wkt = Wqt + (size_t)DD * DD;
  u16*   Wvt = Wkt + (size_t)DD * DD;

  conv_x<<<2048, 256, 0, stream>>>(x, mem, Ab);
  conv_w<<<1024, 256, 0, stream>>>(Wq, Wk, Wv, Wo, Wqt, Wkt, Wvt, Wot);

  // G1: QKV projection  [33024 x 2304] = Ab @ [Wqt|Wkt|Wvt]^T  (+bias, -> bf16)
  gemm256<0><<<dim3(9, 129), 512, 131072, stream>>>(
      Ab, Wqt, Wkt, Wvt, bq, bk, bv, Qb, Kb, Vb, nullptr, DD / 64);

  // G2a: S = Q @ K^T * scale  (per batch, K-rows remapped over [x;memory])
  gemm_bt<1><<<dim3(2, 3, BB), 256, 0, stream>>>(Qb, Kb, nullptr, nullptr, S, DD);

  // softmax rows -> P (bf16, zero-padded to 320 cols)
  softmax_k<<<8192, 256, 0, stream>>>(S, P);

  // Vt[b][d][t]  (writes over dead Qb/Kb region)
  transpose_v<<<dim3(12, 5, BB), 256, 0, stream>>>(Vb, Vt);

  // G2c: O = P @ Vt^T  (per batch, K=320)
  gemm_bt<2><<<dim3(2, 6, BB), 256, 0, stream>>>(P, Vt, nullptr, O, nullptr, TP);

  // G3: out = O @ Wot^T + bo  (fp32)
  gemm256<1><<<dim3(3, 128), 512, 131072, stream>>>(
      O, Wot, nullptr, nullptr, bo, nullptr, nullptr,
      nullptr, nullptr, nullptr, out, DD / 64);
}

// Round 4
// 349.113 us; speedup vs baseline: 1.1880x; 1.0457x over previous
//
#include <hip/hip_runtime.h>
#include <hip/hip_bf16.h>

typedef __attribute__((ext_vector_type(4))) float f32x4;
typedef __attribute__((ext_vector_type(8))) short short8;
typedef __attribute__((ext_vector_type(4))) unsigned short us4;
typedef unsigned short u16;

#define DEVI __device__ __forceinline__

#define BB 128      // batches
#define NN 256      // input patches per batch
#define MMEM 8      // memory tokens
#define DD 768      // embed dim
#define TT 264      // N + M
#define TP 320      // T padded (zeros in P cols 264..319)
#define SP 384      // S col padding (3 x 128 tiles)
#define AROWS2 33024  // 129*256: rows for the 256-tile GEMMs (x .. memory .. zero pad)

DEVI u16 f2bf(float f) {
  __hip_bfloat16 b = __float2bfloat16(f);
  u16 u; __builtin_memcpy(&u, &b, 2); return u;
}

DEVI void gload_lds16(const void* g, void* l) {
  __builtin_amdgcn_global_load_lds((const __attribute__((address_space(1))) void*)g,
                                   (__attribute__((address_space(3))) void*)l, 16, 0, 0);
}

// ---------------- conversion kernels ----------------

__global__ __launch_bounds__(256)
void conv_x(const float* __restrict__ x, const float* __restrict__ mem, u16* __restrict__ Ab) {
  const long total4 = (long)AROWS2 * DD / 4;
  for (long i = (long)blockIdx.x * blockDim.x + threadIdx.x; i < total4;
       i += (long)gridDim.x * blockDim.x) {
    long e = i * 4;
    int row = (int)(e / DD);
    int cb  = (int)(e % DD);
    f32x4 v = {0.f, 0.f, 0.f, 0.f};
    if (row < BB * NN)             v = *(const f32x4*)(x   + (size_t)row * DD + cb);
    else if (row < BB * NN + MMEM) v = *(const f32x4*)(mem + (size_t)(row - BB * NN) * DD + cb);
    us4 o = {f2bf(v[0]), f2bf(v[1]), f2bf(v[2]), f2bf(v[3])};
    *(us4*)(Ab + e) = o;
  }
}

__global__ __launch_bounds__(256)
void conv_w(const float* __restrict__ Wq, const float* __restrict__ Wk,
            const float* __restrict__ Wv, const float* __restrict__ Wo,
            u16* __restrict__ Wqt, u16* __restrict__ Wkt,
            u16* __restrict__ Wvt, u16* __restrict__ Wot) {
  const int total = 4 * DD * DD;
  for (int i = blockIdx.x * blockDim.x + threadIdx.x; i < total;
       i += gridDim.x * blockDim.x) {
    int mat = i / (DD * DD), rem = i % (DD * DD);
    int j = rem / DD, d = rem % DD;
    const float* W = (mat == 0) ? Wq : (mat == 1) ? Wk : (mat == 2) ? Wv : Wo;
    u16* Wt = (mat == 0) ? Wqt : (mat == 1) ? Wkt : (mat == 2) ? Wvt : Wot;
    Wt[(size_t)j * DD + d] = f2bf(W[(size_t)d * DD + j]);
  }
}

// ================= 256x256 8-wave phase-pipelined B^T GEMM (K = 768) =================
// T2 st_16x32 swizzle + T3/T4 counted vmcnt + T5 setprio + T1 bijective XCD swizzle.
// Round-4 change vs round-3: sched_barrier(0) ONLY after each lgkmcnt(0) (rule 18);
// all other SCBs removed (m141: liberal sched_barrier(0) pinning cost 874->510 TF).
// LDS: 2 slots x (A 32KB + B 32KB) = 128KB dynamic. Subtile = 16 rows x 32 cols bf16
// = 1024B. Swizzle applied via permuted per-lane SOURCE addresses (linear LDS dest)
// and on ds_read addr (verified correct in round 3: bank conflicts == 0).
// MODE 0: QKV projection (A=Ab, B by tn/3 among Wq/Wk/Wv^T, bias, bf16 out x3)
// MODE 1: out = A @ B^T + bias (fp32 out)

#define BAR()   __builtin_amdgcn_s_barrier()
#define SCB()   __builtin_amdgcn_sched_barrier(0)
#define LGKM0() asm volatile("s_waitcnt lgkmcnt(0)" ::: "memory")
#define VM4()   asm volatile("s_waitcnt vmcnt(4)" ::: "memory")

#define STG(gb, isB, ss, rg, kt) do {                                          \
    const u16* _s = (gb) + (size_t)((rg) * 16 + srow) * DD + (kt) * 64 + scol; \
    char* _d = smem + (ss) * 65536 + (isB) * 32768 + (rg) * 2048;              \
    gload_lds16(_s, _d);                                                       \
    gload_lds16(_s + 32, _d + 1024);                                           \
  } while (0)

// staging subtile sets (consumption-ordered): wave w stages rg, both col-groups
#define STG_A0(ss, kt) STG(Ab, 0, ss, ((w & 3) | ((w & 4) << 1)), kt)
#define STG_B0(ss, kt) STG(Bb, 1, ss, ((w & 1) | ((w & 6) << 1)), kt)
#define STG_A1(ss, kt) STG(Ab, 0, ss, (((w & 3) | ((w & 4) << 1)) + 4), kt)
#define STG_B1(ss, kt) STG(Bb, 1, ss, (((w & 1) | ((w & 6) << 1)) + 2), kt)

#define RD_A(dst, s, QM)                                                          \
  _Pragma("unroll") for (int mi = 0; mi < 4; ++mi)                                \
  _Pragma("unroll") for (int ks = 0; ks < 2; ++ks)                                \
    dst[mi][ks] = *(const short8*)(smem + (s) * 65536 +                           \
                    ((wm * 8 + (QM) * 4 + mi) * 2 + ks) * 1024 + fbase);

#define RD_B(dst, s, QN)                                                          \
  _Pragma("unroll") for (int ni = 0; ni < 2; ++ni)                                \
  _Pragma("unroll") for (int ks = 0; ks < 2; ++ks)                                \
    dst[ni][ks] = *(const short8*)(smem + (s) * 65536 + 32768 +                   \
                    ((wn * 4 + (QN) * 2 + ni) * 2 + ks) * 1024 + fbase);

#define MM(FA, FB, QM, QN)                                                        \
  _Pragma("unroll") for (int mi = 0; mi < 4; ++mi)                                \
  _Pragma("unroll") for (int ni = 0; ni < 2; ++ni)                                \
  _Pragma("unroll") for (int ks = 0; ks < 2; ++ks)                                \
    acc[(QM)*4+mi][(QN)*2+ni] = __builtin_amdgcn_mfma_f32_16x16x32_bf16(          \
        FA[mi][ks], FB[ni][ks], acc[(QM)*4+mi][(QN)*2+ni], 0, 0, 0);

template<int MODE>
__global__ __launch_bounds__(512)
void gemm256(const u16* __restrict__ A, const u16* __restrict__ Bq,
             const u16* __restrict__ Bk, const u16* __restrict__ Bv,
             const float* __restrict__ b0, const float* __restrict__ b1,
             const float* __restrict__ b2,
             u16* __restrict__ Oq, u16* __restrict__ Ok, u16* __restrict__ Ov,
             float* __restrict__ FO, int NT)
{
  extern __shared__ char smem[];
  const int tid = threadIdx.x;
  const int l = tid & 63;
  const int w = tid >> 6;           // wave 0..7
  const int wm = w >> 2, wn = w & 3;

  // T1: bijective XCD swizzle (m204). Consecutive wg per XCD chunk; tn fastest
  // within a chunk -> the gridDim.x blocks sharing an A-panel stay on one XCD.
  const int nwg = gridDim.x * gridDim.y;
  const int lin = blockIdx.y * gridDim.x + blockIdx.x;
  const int qq = nwg >> 3, rr = nwg & 7;
  const int xcd = lin & 7, idx = lin >> 3;
  const int wg = (xcd < rr ? xcd * (qq + 1) : rr * (qq + 1) + (xcd - rr) * qq) + idx;
  const int tn = wg % gridDim.x, tm = wg / gridDim.x;

  const u16* Ab = A + (size_t)tm * 256 * DD;
  const u16* Bb;
  int matsel = 0;
  if constexpr (MODE == 0) {
    matsel = tn / 3;
    const u16* Wp = (matsel == 0) ? Bq : (matsel == 1) ? Bk : Bv;
    Bb = Wp + (size_t)(tn % 3) * 256 * DD;
  } else {
    Bb = Bq + (size_t)tn * 256 * DD;
  }

  // staging lane constants: lane i writes LDS subtile bytes [16i,16i+16); its
  // pre-swizzled source chunk is j = i (i<32) else i^2.
  const int jj = (l < 32) ? l : (l ^ 2);
  const int srow = jj >> 2;
  const int scol = (jj & 3) * 8;
  // frag ds_read byte base within a subtile, swizzled
  const int fbase = (((l & 15) * 64) + ((l >> 4) * 16)) ^ (((l >> 3) & 1) << 5);

  f32x4 acc[8][4];
  #pragma unroll
  for (int i = 0; i < 8; ++i)
    #pragma unroll
    for (int jx = 0; jx < 4; ++jx) acc[i][jx] = (f32x4){0.f, 0.f, 0.f, 0.f};

  short8 fa0[4][2], fa1[4][2], fb0[2][2], fb1[2][2];

  // prologue: stage K-tile 0 into slot 0 (sets A0,B0,A1,B1)
  STG_A0(0, 0); STG_B0(0, 0); STG_A1(0, 0); STG_B1(0, 0);
  VM4(); BAR();

  for (int g = 0; g < NT; ++g) {
    const int s = g & 1, ss = s ^ 1;
    const int st = (g + 1 < NT) ? (g + 1) : 0;   // clamp: last group stages a dead tile

    // phase 0: quadrant (0,0)
    RD_A(fa0, s, 0); RD_B(fb0, s, 0);
    STG_A0(ss, st);
    BAR(); LGKM0(); SCB();
    __builtin_amdgcn_s_setprio(1); MM(fa0, fb0, 0, 0); __builtin_amdgcn_s_setprio(0);
    VM4(); BAR();

    // phase 1: quadrant (1,0)
    RD_A(fa1, s, 1);
    STG_B0(ss, st);
    BAR(); LGKM0(); SCB();
    __builtin_amdgcn_s_setprio(1); MM(fa1, fb0, 1, 0); __builtin_amdgcn_s_setprio(0);
    VM4(); BAR();

    // phase 2: quadrant (1,1)
    RD_B(fb1, s, 1);
    STG_A1(ss, st);
    BAR(); LGKM0(); SCB();
    __builtin_amdgcn_s_setprio(1); MM(fa1, fb1, 1, 1); __builtin_amdgcn_s_setprio(0);
    BAR();

    // phase 3: quadrant (0,1)
    STG_B1(ss, st);
    BAR(); LGKM0(); SCB();
    __builtin_amdgcn_s_setprio(1); MM(fa0, fb1, 0, 1); __builtin_amdgcn_s_setprio(0);
    VM4(); BAR();
  }

  // epilogue
  const int fr = l & 15, fro = (l >> 4) * 4;
  if constexpr (MODE == 0) {
    const float* bias = (matsel == 0) ? b0 : (matsel == 1) ? b1 : b2;
    u16* ob = (matsel == 0) ? Oq : (matsel == 1) ? Ok : Ov;
    const int cb = (tn % 3) * 256 + wn * 64;
    const size_t rb = (size_t)tm * 256 + wm * 128;
    #pragma unroll
    for (int MI = 0; MI < 8; ++MI)
      #pragma unroll
      for (int NI = 0; NI < 4; ++NI) {
        const int col = cb + NI * 16 + fr;
        const float bvv = bias[col];
        #pragma unroll
        for (int r = 0; r < 4; ++r)
          ob[(rb + MI * 16 + fro + r) * DD + col] = f2bf(acc[MI][NI][r] + bvv);
      }
  } else {
    const int cb = tn * 256 + wn * 64;
    const size_t rb = (size_t)tm * 256 + wm * 128;
    #pragma unroll
    for (int MI = 0; MI < 8; ++MI)
      #pragma unroll
      for (int NI = 0; NI < 4; ++NI) {
        const int col = cb + NI * 16 + fr;
        const float bvv = b0[col];
        #pragma unroll
        for (int r = 0; r < 4; ++r)
          FO[(rb + MI * 16 + fro + r) * DD + col] = acc[MI][NI][r] + bvv;
      }
  }
}

// ---------------- old 128x128 B^T GEMM (kept for batched S and PV) ----------------
// MODE 1: S = Q @ K^T * scale, batched, K-rows remapped.  out fp32 S.
// MODE 2: O = P @ Vt^T, batched, K=320.  out bf16 O.

template<int MODE>
__global__ __launch_bounds__(256)
void gemm_bt(const u16* __restrict__ A, const u16* __restrict__ Bm,
             const float* __restrict__ f0,
             u16* __restrict__ U0, float* __restrict__ F0, int Kdim)
{
  const int tid = threadIdx.x;
  const int l  = tid & 63;
  const int w  = tid >> 6;
  const int wm = w >> 1, wn = w & 1;
  const int tm = blockIdx.x, tn = blockIdx.y, z = blockIdx.z;

  __shared__ u16 lsA[128 * 32];
  __shared__ u16 lsB[128 * 32];

  const u16* Abase; int lda;
  if constexpr (MODE == 1)      { Abase = A + ((size_t)z * NN + tm * 128) * DD; lda = DD; }
  else                          { Abase = A + ((size_t)z * NN + tm * 128) * TP; lda = TP; }

  const u16* Bbase; int ldb;
  if constexpr (MODE == 1) { Bbase = Bm; ldb = DD; }
  else                     { Bbase = Bm + ((size_t)z * DD + tn * 128) * TP; ldb = TP; }

  f32x4 acc[4][4];
  #pragma unroll
  for (int i = 0; i < 4; i++)
    #pragma unroll
    for (int j = 0; j < 4; j++) acc[i][j] = (f32x4){0.f, 0.f, 0.f, 0.f};

  const int srow = l >> 2;
  const int scol = (l & 3) * 8;
  const int nkt = Kdim >> 5;

  for (int kt = 0; kt < nkt; ++kt) {
    const int kpos = kt * 32 + scol;
    #pragma unroll
    for (int q = 0; q < 2; ++q) {
      const int r = q * 64 + w * 16 + srow;
      gload_lds16(Abase + (size_t)r * lda + kpos, &lsA[q * 2048 + w * 512]);
    }
    #pragma unroll
    for (int q = 0; q < 2; ++q) {
      const int r = q * 64 + w * 16 + srow;
      const u16* src;
      if constexpr (MODE == 1) {
        const int t = tn * 128 + r;
        const int rr = (t < NN) ? (z * NN + t)
                     : ((t < TT) ? (BB * NN + t - NN) : BB * NN);
        src = Bm + (size_t)rr * DD + kpos;
      } else {
        src = Bbase + (size_t)r * ldb + kpos;
      }
      gload_lds16(src, &lsB[q * 2048 + w * 512]);
    }
    __syncthreads();

    const int fr = l & 15, fk = (l >> 4) * 8;
    short8 fa[4], fb[4];
    #pragma unroll
    for (int mi = 0; mi < 4; mi++)
      fa[mi] = *(const short8*)&lsA[(wm * 64 + mi * 16 + fr) * 32 + fk];
    #pragma unroll
    for (int ni = 0; ni < 4; ni++)
      fb[ni] = *(const short8*)&lsB[(wn * 64 + ni * 16 + fr) * 32 + fk];
    #pragma unroll
    for (int mi = 0; mi < 4; mi++)
      #pragma unroll
      for (int ni = 0; ni < 4; ni++)
        acc[mi][ni] = __builtin_amdgcn_mfma_f32_16x16x32_bf16(fa[mi], fb[ni], acc[mi][ni], 0, 0, 0);
    __syncthreads();
  }

  const int fr  = l & 15;
  const int fro = (l >> 4) * 4;

  if constexpr (MODE == 1) {
    const float scl = 0.03608439182435161f;  // 768^-0.5
    float* Sb = F0 + (size_t)z * NN * SP;
    const int cb = tn * 128 + wn * 64;
    const int rb = tm * 128 + wm * 64;
    #pragma unroll
    for (int mi = 0; mi < 4; mi++)
      #pragma unroll
      for (int ni = 0; ni < 4; ni++)
        #pragma unroll
        for (int r = 0; r < 4; r++)
          Sb[(size_t)(rb + mi * 16 + fro + r) * SP + cb + ni * 16 + fr] = acc[mi][ni][r] * scl;
  } else {
    const int cb = tn * 128 + wn * 64;
    const size_t rb = (size_t)z * NN + tm * 128 + wm * 64;
    #pragma unroll
    for (int mi = 0; mi < 4; mi++)
      #pragma unroll
      for (int ni = 0; ni < 4; ni++)
        #pragma unroll
        for (int r = 0; r < 4; r++)
          U0[(rb + mi * 16 + fro + r) * DD + cb + ni * 16 + fr] = f2bf(acc[mi][ni][r]);
  }
}

// ---------------- softmax: one wave per row of S[32768][384], cols 0..263 valid ----------------

__global__ __launch_bounds__(256)
void softmax_k(const float* __restrict__ S, u16* __restrict__ P) {
  const int l = threadIdx.x & 63;
  const int row = blockIdx.x * 4 + (threadIdx.x >> 6);
  const float* s = S + (size_t)row * SP;
  float v0 = s[l], v1 = s[64 + l], v2 = s[128 + l], v3 = s[192 + l];
  float v4 = (l < 8) ? s[256 + l] : -__builtin_inff();
  float m = fmaxf(fmaxf(fmaxf(v0, v1), fmaxf(v2, v3)), v4);
  #pragma unroll
  for (int off = 32; off; off >>= 1) m = fmaxf(m, __shfl_xor(m, off));
  float e0 = __expf(v0 - m), e1 = __expf(v1 - m), e2 = __expf(v2 - m), e3 = __expf(v3 - m);
  float e4 = (l < 8) ? __expf(v4 - m) : 0.f;
  float sum = e0 + e1 + e2 + e3 + e4;
  #pragma unroll
  for (int off = 32; off; off >>= 1) sum += __shfl_xor(sum, off);
  const float inv = 1.f / sum;
  u16* p = P + (size_t)row * TP;
  p[l] = f2bf(e0 * inv); p[64 + l] = f2bf(e1 * inv);
  p[128 + l] = f2bf(e2 * inv); p[192 + l] = f2bf(e3 * inv);
  if (l < 8) p[256 + l] = f2bf(e4 * inv);
  else       p[256 + l] = 0;
}

// ---------------- V transpose: Vt[b][d][t] (t padded to 320 with zeros) ----------------

__global__ __launch_bounds__(256)
void transpose_v(const u16* __restrict__ V, u16* __restrict__ Vt) {
  __shared__ u16 ls[64 * 66];
  const int b = blockIdx.z;
  const int d0 = blockIdx.x * 64;
  const int t0 = blockIdx.y * 64;
  const int tid = threadIdx.x;
  #pragma unroll
  for (int q = 0; q < 2; ++q) {
    const int idx = q * 256 + tid;
    const int tr = idx >> 3;
    const int dg = (idx & 7) * 8;
    const int t = t0 + tr;
    short8 v = (short8)(short)0;
    if (t < NN)       v = *(const short8*)(V + ((size_t)b * NN + t) * DD + d0 + dg);
    else if (t < TT)  v = *(const short8*)(V + (size_t)(BB * NN + t - NN) * DD + d0 + dg);
    #pragma unroll
    for (int e = 0; e < 8; ++e) ls[tr * 66 + dg + e] = (u16)v[e];
  }
  __syncthreads();
  #pragma unroll
  for (int q = 0; q < 2; ++q) {
    const int idx = q * 256 + tid;
    const int dr = idx >> 3;
    const int tg = (idx & 7) * 8;
    short8 v;
    #pragma unroll
    for (int e = 0; e < 8; ++e) v[e] = (short)ls[(tg + e) * 66 + dr];
    *(short8*)(Vt + ((size_t)b * DD + d0 + dr) * TP + t0 + tg) = v;
  }
}

// ---------------- launch ----------------
// d_out (100.66 MB): Ab [0,50.72M) live conv_x->G1; S [0,50.33M) live G2a->softmax;
//   P [50.72M,71.70M) live softmax->G2c; Wq/Wk/Wv^T [97.12M,100.66M) live conv_w->G1.
//   All dead before G3 overwrites d_out.
// ws (high-water 153.35 MB, under round-2-proven 156.3 MB):
//   Qb@0, Kb@50.72M, Vb@101.45M (live G1 -> G2a/transpose);
//   Vt@0 (62.91M, over dead Qb+Kb-head); O@62.91M (50.33M, over dead Kb-tail+Vb-head);
//   Wot@152.17M (1.18M, live conv_w -> G3).

extern "C" void kernel_launch(void* const* d_in, const int* in_sizes, int n_in,
                              void* d_out, int out_size, void* d_ws, size_t ws_size,
                              hipStream_t stream) {
  const float* x   = (const float*)d_in[0];
  const float* mem = (const float*)d_in[1];
  const float* Wq  = (const float*)d_in[2];
  const float* bq  = (const float*)d_in[3];
  const float* Wk  = (const float*)d_in[4];
  const float* bk  = (const float*)d_in[5];
  const float* Wv  = (const float*)d_in[6];
  const float* bv  = (const float*)d_in[7];
  const float* Wo  = (const float*)d_in[8];
  const float* bo  = (const float*)d_in[9];
  float* out = (float*)d_out;
  (void)ws_size; (void)in_sizes; (void)n_in; (void)out_size;

  const size_t QKV_B = (size_t)AROWS2 * DD * 2;        // 50,724,864
  char* wsb = (char*)d_ws;
  u16* Qb  = (u16*)(wsb);
  u16* Kb  = (u16*)(wsb + QKV_B);
  u16* Vb  = (u16*)(wsb + 2 * QKV_B);
  u16* Vt  = (u16*)(wsb);                              // over dead Qb+Kb head
  u16* O   = (u16*)(wsb + (size_t)BB * DD * TP * 2);   // @62,914,560
  u16* Wot = (u16*)(wsb + 3 * QKV_B);                  // @152,174,592

  u16*   Ab  = (u16*)d_out;                            // live conv_x -> G1
  float* S   = (float*)d_out;                          // live G2a -> softmax
  u16*   P   = (u16*)((char*)d_out + QKV_B);           // live softmax -> G2c
  u16*   Wqt = (u16*)((char*)d_out + 97124352);        // live conv_w -> G1
  u16*   Wkt = Wqt + (size_t)DD * DD;
  u16*   Wvt = Wkt + (size_t)DD * DD;

  conv_x<<<2048, 256, 0, stream>>>(x, mem, Ab);
  conv_w<<<1024, 256, 0, stream>>>(Wq, Wk, Wv, Wo, Wqt, Wkt, Wvt, Wot);

  // G1: QKV projection  [33024 x 2304] = Ab @ [Wqt|Wkt|Wvt]^T  (+bias, -> bf16)
  gemm256<0><<<dim3(9, 129), 512, 131072, stream>>>(
      Ab, Wqt, Wkt, Wvt, bq, bk, bv, Qb, Kb, Vb, nullptr, DD / 64);

  // G2a: S = Q @ K^T * scale  (per batch, K-rows remapped over [x;memory])
  gemm_bt<1><<<dim3(2, 3, BB), 256, 0, stream>>>(Qb, Kb, nullptr, nullptr, S, DD);

  // softmax rows -> P (bf16, zero-padded to 320 cols)
  softmax_k<<<8192, 256, 0, stream>>>(S, P);

  // Vt[b][d][t]  (writes over dead Qb/Kb region)
  transpose_v<<<dim3(12, 5, BB), 256, 0, stream>>>(Vb, Vt);

  // G2c: O = P @ Vt^T  (per batch, K=320)
  gemm_bt<2><<<dim3(2, 6, BB), 256, 0, stream>>>(P, Vt, nullptr, O, nullptr, TP);

  // G3: out = O @ Wot^T + bo  (fp32)
  gemm256<1><<<dim3(3, 128), 512, 131072, stream>>>(
      O, Wot, nullptr, nullptr, bo, nullptr, nullptr,
      nullptr, nullptr, nullptr, out, DD / 64);
}